// Round 5
// baseline (132.916 us; speedup 1.0000x reference)
//
#include <hip/hip_runtime.h>

// STN forward, LDS-tiled, two channel passes over ONE 70KB buffer.
// R5: 2 blocks/CU (140KB total LDS, 32 waves/CU) so block A stages while
// block B computes; ch1 loads issued before ch0 gather for intra-block
// overlap. Coords persisted, index/weight math recomputed per pass.

constexpr int B = 2, C = 2, D = 128, H = 128, W = 128;
constexpr int HW  = H * W;
constexpr int DHW = D * HW;
constexpr int TD = 16, TH = 16, TW = 16;     // output tile
constexpr int HALO = 4;
constexpr int RD = 25, RH = 25, RWP = 28;    // staged region (w padded to 7 granules)
constexpr int CHF = RD * RH * RWP;           // 17500 floats / channel
constexpr int CHG = CHF / 4;                 // 4375 granules
constexpr int NT = 1024;
constexpr int NSTG = (CHG + NT - 1) / NT;    // 5

__global__ __launch_bounds__(NT, 8) void stn_kernel(
    const float* __restrict__ image,
    const float* __restrict__ ddf,
    float* __restrict__ out)
{
    __shared__ float smem[CHF];              // 70000 B -> 2 blocks/CU

    const int blk = blockIdx.x;
    const int b   = blk >> 9;
    const int tb  = blk & 511;
    const int t0d = (tb >> 6) * TD, t0h = ((tb >> 3) & 7) * TH, t0w = (tb & 7) * TW;
    const int lo_d = max(t0d - HALO, 0), lo_h = max(t0h - HALO, 0), lo_w = max(t0w - HALO, 0);
    const int hi_d = min(t0d + TD + HALO, D - 1);
    const int hi_h = min(t0h + TH + HALO, H - 1);
    const int hi_w = min(t0w + TW + HALO, W - 1);
    const float* imgb = image + (size_t)b * C * DHW;
    const int tid = threadIdx.x;

    // staging global offsets (reused for both channels)
    int soff[NSTG];
#pragma unroll
    for (int i = 0; i < NSTG; ++i) {
        int g = tid + i * NT; if (g >= CHG) g = CHG - 1;
        int row = g / 7, rw = (g - row * 7) * 4;
        int rd = row / RH, rh = row - rd * RH;
        soff[i] = min(lo_d + rd, D - 1) * HW + min(lo_h + rh, H - 1) * W
                + min(lo_w + rw, W - 4);
    }

    // issue ch0 staging loads
    float4 stg[NSTG];
#pragma unroll
    for (int i = 0; i < NSTG; ++i)
        stg[i] = *reinterpret_cast<const float4*>(imgb + soff[i]);

    // ddf load + clamped coords (persisted across both passes)
    const int dl = tid >> 6, hl = (tid >> 2) & 15, wq = tid & 3;
    const int d = t0d + dl, h = t0h + hl, w4 = t0w + wq * 4;
    const int sidx = d * HW + h * W + w4;
    const float* dp = ddf + (size_t)b * 3 * DHW + sidx;
    float4 fdd = *reinterpret_cast<const float4*>(dp);
    float4 fdh = *reinterpret_cast<const float4*>(dp + DHW);
    float4 fdw = *reinterpret_cast<const float4*>(dp + 2 * DHW);

    float cdk[4], chk[4], cwk[4];
    {
        const float dd[4] = {fdd.x, fdd.y, fdd.z, fdd.w};
        const float dh[4] = {fdh.x, fdh.y, fdh.z, fdh.w};
        const float dw[4] = {fdw.x, fdw.y, fdw.z, fdw.w};
#pragma unroll
        for (int k = 0; k < 4; ++k) {
            cdk[k] = fminf(fmaxf((float)d + dd[k], 0.0f), (float)(D - 1));
            chk[k] = fminf(fmaxf((float)h + dh[k], 0.0f), (float)(H - 1));
            cwk[k] = fminf(fmaxf((float)(w4 + k) + dw[k], 0.0f), (float)(W - 1));
        }
    }

    // write ch0 to LDS
#pragma unroll
    for (int i = 0; i < NSTG; ++i) {
        int g = tid + i * NT; if (g >= CHG) g = CHG - 1;
        *reinterpret_cast<float4*>(&smem[g * 4]) = stg[i];
    }
    __syncthreads();

    // issue ch1 staging loads now — they complete under the ch0 gather
#pragma unroll
    for (int i = 0; i < NSTG; ++i)
        stg[i] = *reinterpret_cast<const float4*>(imgb + DHW + soff[i]);

    auto gather_store = [&](const float* gimg, float* optr) {
        float acc[4];
#pragma unroll
        for (int k = 0; k < 4; ++k) {
            float cd = cdk[k], ch = chk[k], cw = cwk[k];
            float d0f = floorf(cd), h0f = floorf(ch), w0f = floorf(cw);
            float fd = cd - d0f, fh = ch - h0f, fw = cw - w0f;
            int d0 = (int)d0f, h0 = (int)h0f, w0 = (int)w0f;
            int d1 = min(d0 + 1, D - 1);
            int h1 = min(h0 + 1, H - 1);
            int w1 = min(w0 + 1, W - 1);
            bool ok = (d0 >= lo_d) & (d1 <= hi_d) & (h0 >= lo_h) & (h1 <= hi_h)
                    & (w0 >= lo_w) & (w1 <= hi_w);
            float gd = 1.0f - fd, gh = 1.0f - fh, gw = 1.0f - fw;
            float w00 = gh * gw, w01 = gh * fw, w10 = fh * gw, w11 = fh * fw;
            int ld0 = d0 - lo_d, ld1 = d1 - lo_d;
            int lh0 = h0 - lo_h, lh1 = h1 - lo_h;
            int lw0 = w0 - lo_w, lw1 = w1 - lo_w;
            int i00 = (ld0 * RH + lh0) * RWP;
            int i01 = (ld0 * RH + lh1) * RWP;
            int i10 = (ld1 * RH + lh0) * RWP;
            int i11 = (ld1 * RH + lh1) * RWP;
            float p0 = smem[i00 + lw0] * w00 + smem[i00 + lw1] * w01
                     + smem[i01 + lw0] * w10 + smem[i01 + lw1] * w11;
            float p1 = smem[i10 + lw0] * w00 + smem[i10 + lw1] * w01
                     + smem[i11 + lw0] * w10 + smem[i11 + lw1] * w11;
            float v = gd * p0 + fd * p1;
            if (!ok) {  // rare |ddf|>4: exact global fallback
                int o00 = d0 * HW + h0 * W, o01 = d0 * HW + h1 * W;
                int o10 = d1 * HW + h0 * W, o11 = d1 * HW + h1 * W;
                float q0 = gimg[o00 + w0] * w00 + gimg[o00 + w1] * w01
                         + gimg[o01 + w0] * w10 + gimg[o01 + w1] * w11;
                float q1 = gimg[o10 + w0] * w00 + gimg[o10 + w1] * w01
                         + gimg[o11 + w0] * w10 + gimg[o11 + w1] * w11;
                v = gd * q0 + fd * q1;
            }
            acc[k] = v;
        }
        *reinterpret_cast<float4*>(optr) = make_float4(acc[0], acc[1], acc[2], acc[3]);
    };

    // ch0 gather + store (ch1 loads in flight)
    gather_store(imgb, out + ((size_t)b * C + 0) * DHW + sidx);
    __syncthreads();   // all ch0 reads complete before overwrite

    // write ch1 to LDS
#pragma unroll
    for (int i = 0; i < NSTG; ++i) {
        int g = tid + i * NT; if (g >= CHG) g = CHG - 1;
        *reinterpret_cast<float4*>(&smem[g * 4]) = stg[i];
    }
    __syncthreads();

    gather_store(imgb + DHW, out + ((size_t)b * C + 1) * DHW + sidx);
}

extern "C" void kernel_launch(void* const* d_in, const int* in_sizes, int n_in,
                              void* d_out, int out_size, void* d_ws, size_t ws_size,
                              hipStream_t stream) {
    const float* image = (const float*)d_in[0];
    const float* ddf   = (const float*)d_in[1];
    float* out = (float*)d_out;

    int grid = B * 512;   // 8x8x8 tiles of 16^3 per batch
    stn_kernel<<<grid, NT, 0, stream>>>(image, ddf, out);
}

// Round 6
// 106.440 us; speedup vs baseline: 1.2487x; 1.2487x over previous
//
#include <hip/hip_runtime.h>

// STN forward, LDS-tiled, two channel passes over ONE buffer, staged via
// async global_load_lds (zero staging VGPRs -> no spills, unlike R5).
// 70656B LDS/block -> 2 blocks/CU: block A stages while block B gathers.

constexpr int B = 2, C = 2, D = 128, H = 128, W = 128;
constexpr int HW  = H * W;
constexpr int DHW = D * HW;
constexpr int TD = 16, TH = 16, TW = 16;     // output tile
constexpr int HALO = 4;
constexpr int RD = 25, RH = 25, RWP = 28;    // staged region (w padded: 7 granules)
constexpr int CHF = RD * RH * RWP;           // 17500 floats / channel
constexpr int CHG = CHF / 4;                 // 4375 16B granules
constexpr int NT = 1024;
constexpr int CHG_PAD = 4416;                // 69 waves * 64 (wave-multiple)
constexpr int TAIL = CHG_PAD - 4 * NT;       // 320 (5 full waves)

__device__ __forceinline__ void gload_lds16(const float* g, float* l) {
    __builtin_amdgcn_global_load_lds(
        (const __attribute__((address_space(1))) void*)g,
        (__attribute__((address_space(3))) void*)l, 16, 0, 0);
}

__global__ __launch_bounds__(NT, 8) void stn_kernel(
    const float* __restrict__ image,
    const float* __restrict__ ddf,
    float* __restrict__ out)
{
    __shared__ float smem[CHG_PAD * 4];      // 70656 B

    const int blk = blockIdx.x;
    const int b   = blk >> 9;
    const int tb  = blk & 511;
    const int t0d = (tb >> 6) * TD, t0h = ((tb >> 3) & 7) * TH, t0w = (tb & 7) * TW;
    const int lo_d = max(t0d - HALO, 0), lo_h = max(t0h - HALO, 0), lo_w = max(t0w - HALO, 0);
    const int hi_d = min(t0d + TD + HALO, D - 1);
    const int hi_h = min(t0h + TH + HALO, H - 1);
    const int hi_w = min(t0w + TW + HALO, W - 1);
    const float* imgb = image + (size_t)b * C * DHW;
    const int tid = threadIdx.x;

    // granule g -> global offset (row-clamped at volume edge)
    auto gsrc_off = [&](int g) {
        int row = g / 7;                 // g already clamped by caller if needed
        int rw  = (g - row * 7) * 4;
        int rd  = row / RH;
        int rh  = row - rd * RH;
        return min(lo_d + rd, D - 1) * HW + min(lo_h + rh, H - 1) * W
             + min(lo_w + rw, W - 4);
    };

    // issue one channel's staging: async global->LDS, no VGPR round trip
    auto issue_stage = [&](const float* src) {
#pragma unroll
        for (int i = 0; i < 4; ++i) {
            int g = tid + i * NT;                       // < 4096 < CHG
            gload_lds16(src + gsrc_off(g), &smem[g * 4]);
        }
        if (tid < TAIL) {                               // wave-uniform tail
            int g = tid + 4 * NT;                       // 4096..4415
            int gq = min(g, CHG - 1);                   // clamp SOURCE only
            gload_lds16(src + gsrc_off(gq), &smem[g * 4]);
        }
    };

    issue_stage(imgb);                                  // ch0 loads in flight

    // ddf load + clamped coords (persisted across both passes)
    const int dl = tid >> 6, hl = (tid >> 2) & 15, wq = tid & 3;
    const int d = t0d + dl, h = t0h + hl, w4 = t0w + wq * 4;
    const int sidx = d * HW + h * W + w4;
    const float* dp = ddf + (size_t)b * 3 * DHW + sidx;
    float4 fdd = *reinterpret_cast<const float4*>(dp);
    float4 fdh = *reinterpret_cast<const float4*>(dp + DHW);
    float4 fdw = *reinterpret_cast<const float4*>(dp + 2 * DHW);

    float cdk[4], chk[4], cwk[4];
    {
        const float dd[4] = {fdd.x, fdd.y, fdd.z, fdd.w};
        const float dh[4] = {fdh.x, fdh.y, fdh.z, fdh.w};
        const float dw[4] = {fdw.x, fdw.y, fdw.z, fdw.w};
#pragma unroll
        for (int k = 0; k < 4; ++k) {
            cdk[k] = fminf(fmaxf((float)d + dd[k], 0.0f), (float)(D - 1));
            chk[k] = fminf(fmaxf((float)h + dh[k], 0.0f), (float)(H - 1));
            cwk[k] = fminf(fmaxf((float)(w4 + k) + dw[k], 0.0f), (float)(W - 1));
        }
    }

    auto gather_store = [&](const float* gimg, float* optr) {
        float acc[4];
#pragma unroll
        for (int k = 0; k < 4; ++k) {
            float cd = cdk[k], ch = chk[k], cw = cwk[k];
            float d0f = floorf(cd), h0f = floorf(ch), w0f = floorf(cw);
            float fd = cd - d0f, fh = ch - h0f, fw = cw - w0f;
            int d0 = (int)d0f, h0 = (int)h0f, w0 = (int)w0f;
            int d1 = min(d0 + 1, D - 1);
            int h1 = min(h0 + 1, H - 1);
            int w1 = min(w0 + 1, W - 1);
            bool ok = (d0 >= lo_d) & (d1 <= hi_d) & (h0 >= lo_h) & (h1 <= hi_h)
                    & (w0 >= lo_w) & (w1 <= hi_w);
            float gd = 1.0f - fd, gh = 1.0f - fh, gw = 1.0f - fw;
            float w00 = gh * gw, w01 = gh * fw, w10 = fh * gw, w11 = fh * fw;
            int ld0 = d0 - lo_d, ld1 = d1 - lo_d;
            int lh0 = h0 - lo_h, lh1 = h1 - lo_h;
            int lw0 = w0 - lo_w, lw1 = w1 - lo_w;
            int i00 = (ld0 * RH + lh0) * RWP;
            int i01 = (ld0 * RH + lh1) * RWP;
            int i10 = (ld1 * RH + lh0) * RWP;
            int i11 = (ld1 * RH + lh1) * RWP;
            float p0 = smem[i00 + lw0] * w00 + smem[i00 + lw1] * w01
                     + smem[i01 + lw0] * w10 + smem[i01 + lw1] * w11;
            float p1 = smem[i10 + lw0] * w00 + smem[i10 + lw1] * w01
                     + smem[i11 + lw0] * w10 + smem[i11 + lw1] * w11;
            float v = gd * p0 + fd * p1;
            if (!ok) {  // rare (|ddf|>4): exact global fallback
                int o00 = d0 * HW + h0 * W, o01 = d0 * HW + h1 * W;
                int o10 = d1 * HW + h0 * W, o11 = d1 * HW + h1 * W;
                float q0 = gimg[o00 + w0] * w00 + gimg[o00 + w1] * w01
                         + gimg[o01 + w0] * w10 + gimg[o01 + w1] * w11;
                float q1 = gimg[o10 + w0] * w00 + gimg[o10 + w1] * w01
                         + gimg[o11 + w0] * w10 + gimg[o11 + w1] * w11;
                v = gd * q0 + fd * q1;
            }
            acc[k] = v;
        }
        *reinterpret_cast<float4*>(optr) = make_float4(acc[0], acc[1], acc[2], acc[3]);
    };

    asm volatile("s_waitcnt vmcnt(0)" ::: "memory");    // ch0 staged
    __syncthreads();
    gather_store(imgb, out + ((size_t)b * C + 0) * DHW + sidx);

    __syncthreads();                                    // all ch0 reads done
    issue_stage(imgb + DHW);                            // ch1 loads
    asm volatile("s_waitcnt vmcnt(0)" ::: "memory");
    __syncthreads();
    gather_store(imgb + DHW, out + ((size_t)b * C + 1) * DHW + sidx);
}

extern "C" void kernel_launch(void* const* d_in, const int* in_sizes, int n_in,
                              void* d_out, int out_size, void* d_ws, size_t ws_size,
                              hipStream_t stream) {
    const float* image = (const float*)d_in[0];
    const float* ddf   = (const float*)d_in[1];
    float* out = (float*)d_out;

    int grid = B * 512;   // 8x8x8 tiles of 16^3 per batch
    stn_kernel<<<grid, NT, 0, stream>>>(image, ddf, out);
}

// Round 7
// 57.813 us; speedup vs baseline: 2.2991x; 1.8411x over previous
//
#include <hip/hip_runtime.h>

// STN forward, LDS-tiled (R4 structure: 1 block/CU, both channels in LDS),
// staged via async global_load_lds (zero staging VGPRs -> no spills), with
// counted-vmcnt overlap: ch1 staging stays in flight under ch0 compute.
// Order: ddf loads, ch0 stage, ch1 stage -> vmcnt(4)+barrier -> gather ch0
// -> vmcnt(0)+barrier -> store ch0, gather ch1, store ch1.

constexpr int B = 2, C = 2, D = 128, H = 128, W = 128;
constexpr int HW  = H * W;
constexpr int DHW = D * HW;
constexpr int TD = 16, TH = 16, TW = 16;     // output tile
constexpr int HALO = 4;
constexpr int RD = 25, RH = 25, RWP = 28;    // staged region (w padded: 7 granules)
constexpr int CHF = RD * RH * RWP;           // 17500 floats / channel
constexpr int CHG = CHF / 4;                 // 4375 16B granules / channel
constexpr int NT = 1024;
constexpr int CHG_PAD = 4416;                // 69 waves (wave-multiple)
constexpr int TAIL = CHG_PAD - 4 * NT;       // 320 = 5 full waves

__device__ __forceinline__ void gload_lds16(const float* g, float* l) {
    __builtin_amdgcn_global_load_lds(
        (const __attribute__((address_space(1))) void*)g,
        (__attribute__((address_space(3))) void*)l, 16, 0, 0);
}

__global__ __launch_bounds__(NT) void stn_kernel(
    const float* __restrict__ image,
    const float* __restrict__ ddf,
    float* __restrict__ out)
{
    __shared__ float smem[2 * CHG_PAD * 4];  // 141312 B -> 1 block/CU

    const int blk = blockIdx.x;
    const int b   = blk >> 9;
    const int tb  = blk & 511;
    const int t0d = (tb >> 6) * TD, t0h = ((tb >> 3) & 7) * TH, t0w = (tb & 7) * TW;
    const int lo_d = max(t0d - HALO, 0), lo_h = max(t0h - HALO, 0), lo_w = max(t0w - HALO, 0);
    const int hi_d = min(t0d + TD + HALO, D - 1);
    const int hi_h = min(t0h + TH + HALO, H - 1);
    const int hi_w = min(t0w + TW + HALO, W - 1);
    const float* imgb = image + (size_t)b * C * DHW;
    const int tid = threadIdx.x;

    // ---- ddf loads FIRST (their compiler-inserted wait is then free) ----
    const int dl = tid >> 6, hl = (tid >> 2) & 15, wq = tid & 3;
    const int d = t0d + dl, h = t0h + hl, w4 = t0w + wq * 4;
    const int sidx = d * HW + h * W + w4;
    const float* dp = ddf + (size_t)b * 3 * DHW + sidx;
    float4 fdd = *reinterpret_cast<const float4*>(dp);
    float4 fdh = *reinterpret_cast<const float4*>(dp + DHW);
    float4 fdw = *reinterpret_cast<const float4*>(dp + 2 * DHW);
    asm volatile("" ::: "memory");   // pin issue order: ddf | ch0 | ch1

    // granule g -> global offset (row-clamped at volume edge)
    auto gsrc_off = [&](int g) {
        int row = g / 7;
        int rw  = (g - row * 7) * 4;
        int rd  = row / RH;
        int rh  = row - rd * RH;
        return min(lo_d + rd, D - 1) * HW + min(lo_h + rh, H - 1) * W
             + min(lo_w + rw, W - 4);
    };

    // async stage one channel into smem[bufBase..]; whole-wave tail branch
    auto issue_stage = [&](const float* src, int bufBase) {
#pragma unroll
        for (int i = 0; i < 4; ++i) {
            int g = tid + i * NT;                       // < 4096 < CHG
            gload_lds16(src + gsrc_off(g), &smem[bufBase + g * 4]);
        }
        if (tid < TAIL) {                               // 5 full waves
            int g = tid + 4 * NT;                       // 4096..4415
            int gq = min(g, CHG - 1);                   // clamp SOURCE only
            gload_lds16(src + gsrc_off(gq), &smem[bufBase + g * 4]);
        }
    };

    issue_stage(imgb, 0);                               // ch0
    asm volatile("" ::: "memory");
    issue_stage(imgb + DHW, CHG_PAD * 4);               // ch1 (stays in flight)
    asm volatile("" ::: "memory");

    // clamped coords (persisted across both passes; ~12 VGPR)
    float cdk[4], chk[4], cwk[4];
    {
        const float dd[4] = {fdd.x, fdd.y, fdd.z, fdd.w};
        const float dh[4] = {fdh.x, fdh.y, fdh.z, fdh.w};
        const float dw[4] = {fdw.x, fdw.y, fdw.z, fdw.w};
#pragma unroll
        for (int k = 0; k < 4; ++k) {
            cdk[k] = fminf(fmaxf((float)d + dd[k], 0.0f), (float)(D - 1));
            chk[k] = fminf(fmaxf((float)h + dh[k], 0.0f), (float)(H - 1));
            cwk[k] = fminf(fmaxf((float)(w4 + k) + dw[k], 0.0f), (float)(W - 1));
        }
    }

    auto gather = [&](const float* lbase, const float* gimg, float* acc) {
#pragma unroll
        for (int k = 0; k < 4; ++k) {
            float cd = cdk[k], ch = chk[k], cw = cwk[k];
            float d0f = floorf(cd), h0f = floorf(ch), w0f = floorf(cw);
            float fd = cd - d0f, fh = ch - h0f, fw = cw - w0f;
            int d0 = (int)d0f, h0 = (int)h0f, w0 = (int)w0f;
            int d1 = min(d0 + 1, D - 1);
            int h1 = min(h0 + 1, H - 1);
            int w1 = min(w0 + 1, W - 1);
            bool ok = (d0 >= lo_d) & (d1 <= hi_d) & (h0 >= lo_h) & (h1 <= hi_h)
                    & (w0 >= lo_w) & (w1 <= hi_w);
            float gd = 1.0f - fd, gh = 1.0f - fh, gw = 1.0f - fw;
            float w00 = gh * gw, w01 = gh * fw, w10 = fh * gw, w11 = fh * fw;
            int ld0 = d0 - lo_d, ld1 = d1 - lo_d;
            int lh0 = h0 - lo_h, lh1 = h1 - lo_h;
            int lw0 = w0 - lo_w, lw1 = w1 - lo_w;
            int i00 = (ld0 * RH + lh0) * RWP;
            int i01 = (ld0 * RH + lh1) * RWP;
            int i10 = (ld1 * RH + lh0) * RWP;
            int i11 = (ld1 * RH + lh1) * RWP;
            float p0 = lbase[i00 + lw0] * w00 + lbase[i00 + lw1] * w01
                     + lbase[i01 + lw0] * w10 + lbase[i01 + lw1] * w11;
            float p1 = lbase[i10 + lw0] * w00 + lbase[i10 + lw1] * w01
                     + lbase[i11 + lw0] * w10 + lbase[i11 + lw1] * w11;
            float v = gd * p0 + fd * p1;
            if (!ok) {  // rare (|ddf|>4): exact global fallback
                int o00 = d0 * HW + h0 * W, o01 = d0 * HW + h1 * W;
                int o10 = d1 * HW + h0 * W, o11 = d1 * HW + h1 * W;
                float q0 = gimg[o00 + w0] * w00 + gimg[o00 + w1] * w01
                         + gimg[o01 + w0] * w10 + gimg[o01 + w1] * w11;
                float q1 = gimg[o10 + w0] * w00 + gimg[o10 + w1] * w01
                         + gimg[o11 + w0] * w10 + gimg[o11 + w1] * w11;
                v = gd * q0 + fd * q1;
            }
            acc[k] = v;
        }
    };

    // ch0 ready (ddf + ch0 drained; <=4 ch1 loads still in flight)
    asm volatile("s_waitcnt vmcnt(4)" ::: "memory");
    __builtin_amdgcn_s_barrier();

    float acc0[4];
    gather(smem, imgb, acc0);                 // ch1 staging hides under this

    // ch1 ready: each wave drains its own loads, then all waves sync
    asm volatile("s_waitcnt vmcnt(0)" ::: "memory");
    __builtin_amdgcn_s_barrier();

    *reinterpret_cast<float4*>(out + ((size_t)b * C + 0) * DHW + sidx) =
        make_float4(acc0[0], acc0[1], acc0[2], acc0[3]);

    float acc1[4];
    gather(smem + CHG_PAD * 4, imgb + DHW, acc1);
    *reinterpret_cast<float4*>(out + ((size_t)b * C + 1) * DHW + sidx) =
        make_float4(acc1[0], acc1[1], acc1[2], acc1[3]);
}

extern "C" void kernel_launch(void* const* d_in, const int* in_sizes, int n_in,
                              void* d_out, int out_size, void* d_ws, size_t ws_size,
                              hipStream_t stream) {
    const float* image = (const float*)d_in[0];
    const float* ddf   = (const float*)d_in[1];
    float* out = (float*)d_out;

    int grid = B * 512;   // 8x8x8 tiles of 16^3 per batch
    stn_kernel<<<grid, NT, 0, stream>>>(image, ddf, out);
}

// Round 8
// 53.750 us; speedup vs baseline: 2.4729x; 1.0756x over previous
//
#include <hip/hip_runtime.h>

// STN forward, LDS-tiled, ONE 70.6KB channel buffer reused for two passes.
// R8: 2 blocks/CU (141KB aggregate LDS, VGPR<=64 target) -> block A's
// vmcnt staging wait hides under block B's gather compute. Staging via
// async global_load_lds (zero staging VGPRs). NO min-waves launch bound
// (R5/R6 lesson: (1024,8) causes catastrophic scratch spills).

constexpr int B = 2, C = 2, D = 128, H = 128, W = 128;
constexpr int HW  = H * W;
constexpr int DHW = D * HW;
constexpr int TD = 16, TH = 16, TW = 16;     // output tile
constexpr int HALO = 4;
constexpr int RD = 25, RH = 25, RWP = 28;    // staged region (w padded: 7 granules)
constexpr int CHF = RD * RH * RWP;           // 17500 floats / channel
constexpr int CHG = CHF / 4;                 // 4375 16B granules / channel
constexpr int NT = 1024;
constexpr int CHG_PAD = 4416;                // 69 waves (wave-multiple)
constexpr int TAIL = CHG_PAD - 4 * NT;       // 320 = 5 full waves

__device__ __forceinline__ void gload_lds16(const float* g, float* l) {
    __builtin_amdgcn_global_load_lds(
        (const __attribute__((address_space(1))) void*)g,
        (__attribute__((address_space(3))) void*)l, 16, 0, 0);
}

__global__ __launch_bounds__(NT) void stn_kernel(
    const float* __restrict__ image,
    const float* __restrict__ ddf,
    float* __restrict__ out)
{
    __shared__ float smem[CHG_PAD * 4];      // 70656 B -> 2 blocks/CU

    const int blk = blockIdx.x;
    const int b   = blk >> 9;
    const int tb  = blk & 511;
    const int t0d = (tb >> 6) * TD, t0h = ((tb >> 3) & 7) * TH, t0w = (tb & 7) * TW;
    const int lo_d = max(t0d - HALO, 0), lo_h = max(t0h - HALO, 0), lo_w = max(t0w - HALO, 0);
    const int hi_d = min(t0d + TD + HALO, D - 1);
    const int hi_h = min(t0h + TH + HALO, H - 1);
    const int hi_w = min(t0w + TW + HALO, W - 1);
    const float* imgb = image + (size_t)b * C * DHW;
    const int tid = threadIdx.x;

    // ---- ddf loads FIRST (compiler's wait for them is then ~free) ----
    const int dl = tid >> 6, hl = (tid >> 2) & 15, wq = tid & 3;
    const int d = t0d + dl, h = t0h + hl, w4 = t0w + wq * 4;
    const int sidx = d * HW + h * W + w4;
    const float* dp = ddf + (size_t)b * 3 * DHW + sidx;
    float4 fdd = *reinterpret_cast<const float4*>(dp);
    float4 fdh = *reinterpret_cast<const float4*>(dp + DHW);
    float4 fdw = *reinterpret_cast<const float4*>(dp + 2 * DHW);
    asm volatile("" ::: "memory");

    // granule g -> global offset (row-clamped at volume edge)
    auto gsrc_off = [&](int g) {
        int row = g / 7;
        int rw  = (g - row * 7) * 4;
        int rd  = row / RH;
        int rh  = row - rd * RH;
        return min(lo_d + rd, D - 1) * HW + min(lo_h + rh, H - 1) * W
             + min(lo_w + rw, W - 4);
    };

    // async stage one channel into smem; tail is 5 whole waves
    auto issue_stage = [&](const float* src) {
#pragma unroll
        for (int i = 0; i < 4; ++i) {
            int g = tid + i * NT;                       // < 4096 < CHG
            gload_lds16(src + gsrc_off(g), &smem[g * 4]);
        }
        if (tid < TAIL) {                               // whole-wave branch
            int g = tid + 4 * NT;                       // 4096..4415
            int gq = min(g, CHG - 1);                   // clamp SOURCE only
            gload_lds16(src + gsrc_off(gq), &smem[g * 4]);
        }
    };

    issue_stage(imgb);                                  // ch0 in flight
    asm volatile("" ::: "memory");

    // clamped coords (persisted across both passes; 12 VGPR)
    float cdk[4], chk[4], cwk[4];
    {
        const float dd[4] = {fdd.x, fdd.y, fdd.z, fdd.w};
        const float dh[4] = {fdh.x, fdh.y, fdh.z, fdh.w};
        const float dw[4] = {fdw.x, fdw.y, fdw.z, fdw.w};
#pragma unroll
        for (int k = 0; k < 4; ++k) {
            cdk[k] = fminf(fmaxf((float)d + dd[k], 0.0f), (float)(D - 1));
            chk[k] = fminf(fmaxf((float)h + dh[k], 0.0f), (float)(H - 1));
            cwk[k] = fminf(fmaxf((float)(w4 + k) + dw[k], 0.0f), (float)(W - 1));
        }
    }

    auto gather = [&](const float* gimg, float* acc) {
#pragma unroll
        for (int k = 0; k < 4; ++k) {
            float cd = cdk[k], ch = chk[k], cw = cwk[k];
            float d0f = floorf(cd), h0f = floorf(ch), w0f = floorf(cw);
            float fd = cd - d0f, fh = ch - h0f, fw = cw - w0f;
            int d0 = (int)d0f, h0 = (int)h0f, w0 = (int)w0f;
            int d1 = min(d0 + 1, D - 1);
            int h1 = min(h0 + 1, H - 1);
            int w1 = min(w0 + 1, W - 1);
            bool ok = (d0 >= lo_d) & (d1 <= hi_d) & (h0 >= lo_h) & (h1 <= hi_h)
                    & (w0 >= lo_w) & (w1 <= hi_w);
            float gd = 1.0f - fd, gh = 1.0f - fh, gw = 1.0f - fw;
            float w00 = gh * gw, w01 = gh * fw, w10 = fh * gw, w11 = fh * fw;
            int ld0 = d0 - lo_d, ld1 = d1 - lo_d;
            int lh0 = h0 - lo_h, lh1 = h1 - lo_h;
            int lw0 = w0 - lo_w, lw1 = w1 - lo_w;
            int i00 = (ld0 * RH + lh0) * RWP;
            int i01 = (ld0 * RH + lh1) * RWP;
            int i10 = (ld1 * RH + lh0) * RWP;
            int i11 = (ld1 * RH + lh1) * RWP;
            float p0 = smem[i00 + lw0] * w00 + smem[i00 + lw1] * w01
                     + smem[i01 + lw0] * w10 + smem[i01 + lw1] * w11;
            float p1 = smem[i10 + lw0] * w00 + smem[i10 + lw1] * w01
                     + smem[i11 + lw0] * w10 + smem[i11 + lw1] * w11;
            float v = gd * p0 + fd * p1;
            if (!ok) {  // rare (|ddf|>4): exact global fallback
                int o00 = d0 * HW + h0 * W, o01 = d0 * HW + h1 * W;
                int o10 = d1 * HW + h0 * W, o11 = d1 * HW + h1 * W;
                float q0 = gimg[o00 + w0] * w00 + gimg[o00 + w1] * w01
                         + gimg[o01 + w0] * w10 + gimg[o01 + w1] * w11;
                float q1 = gimg[o10 + w0] * w00 + gimg[o10 + w1] * w01
                         + gimg[o11 + w0] * w10 + gimg[o11 + w1] * w11;
                v = gd * q0 + fd * q1;
            }
            acc[k] = v;
        }
    };

    // ---- pass 0 ----
    asm volatile("s_waitcnt vmcnt(0)" ::: "memory");    // ch0 staged
    __builtin_amdgcn_s_barrier();
    float acc0[4];
    gather(imgb, acc0);
    *reinterpret_cast<float4*>(out + ((size_t)b * C + 0) * DHW + sidx) =
        make_float4(acc0[0], acc0[1], acc0[2], acc0[3]);

    // all waves done reading ch0 before overwrite
    __builtin_amdgcn_s_barrier();
    asm volatile("" ::: "memory");

    // ---- pass 1 ----
    issue_stage(imgb + DHW);
    asm volatile("s_waitcnt vmcnt(0)" ::: "memory");    // ch1 staged
    __builtin_amdgcn_s_barrier();
    float acc1[4];
    gather(imgb + DHW, acc1);
    *reinterpret_cast<float4*>(out + ((size_t)b * C + 1) * DHW + sidx) =
        make_float4(acc1[0], acc1[1], acc1[2], acc1[3]);
}

extern "C" void kernel_launch(void* const* d_in, const int* in_sizes, int n_in,
                              void* d_out, int out_size, void* d_ws, size_t ws_size,
                              hipStream_t stream) {
    const float* image = (const float*)d_in[0];
    const float* ddf   = (const float*)d_in[1];
    float* out = (float*)d_out;

    int grid = B * 512;   // 8x8x8 tiles of 16^3 per batch
    stn_kernel<<<grid, NT, 0, stream>>>(image, ddf, out);
}